// Round 14
// baseline (184.002 us; speedup 1.0000x reference)
//
#include <hip/hip_runtime.h>
#include <hip/hip_bf16.h>
#include <math.h>

using bf16 = __hip_bfloat16;

typedef __bf16 bf16x8 __attribute__((ext_vector_type(8)));
typedef __bf16 bf16x4 __attribute__((ext_vector_type(4)));
typedef float  f32x4  __attribute__((ext_vector_type(4)));
typedef float  f32x16 __attribute__((ext_vector_type(16)));

constexpr int Bb = 2;
constexpr int Ts = 2048;
constexpr int Cc = 1024;
constexpr int Hh = 16;
constexpr int Dh = 64;
constexpr int Mm = Bb * Ts;        // 4096 rows of x
constexpr int Nqkv = 3 * Cc;       // 3072
constexpr int BHTD = Bb * Hh * Ts * Dh;  // elements per Q/K/V tensor

// async global->LDS, 16B per lane; LDS dest = wave-uniform base + lane*16
__device__ __forceinline__
void gll16(const __bf16* g, __bf16* l)
{
    __builtin_amdgcn_global_load_lds(
        (const __attribute__((address_space(1))) unsigned int*)g,
        (__attribute__((address_space(3))) unsigned int*)l,
        16, 0, 0);
}

// ---------------------------------------------------------------------------
// Merged prep: [0,4096) cvt X fp32->bf16; [4096,4864) transpose W_qkv;
// [4864,5120) transpose W_proj.   (benched, unchanged)
// ---------------------------------------------------------------------------
__global__ __launch_bounds__(256)
void prep_all(const float* __restrict__ x, __bf16* __restrict__ Xb,
              const float* __restrict__ Wq, __bf16* __restrict__ Wqt,
              const float* __restrict__ Wp, __bf16* __restrict__ Wpt)
{
    __shared__ __bf16 tl[64][72];
    const int bid = blockIdx.x;
    const int t = threadIdx.x;

    if (bid < 4096) {
        int i = (bid * 256 + t) * 4;
        float4 v = *(const float4*)(x + i);
        bf16x4 o = { (__bf16)v.x, (__bf16)v.y, (__bf16)v.z, (__bf16)v.w };
        *(bf16x4*)(Xb + i) = o;
        return;
    }
    const float* W; __bf16* Wt; int cols, bx, by;
    if (bid < 4096 + 768) {
        W = Wq; Wt = Wqt; cols = Nqkv;
        bx = (bid - 4096) % 48; by = (bid - 4096) / 48;
    } else {
        W = Wp; Wt = Wpt; cols = Cc;
        bx = (bid - 4864) % 16; by = (bid - 4864) / 16;
    }
    const int c0 = bx * 64;   // N dim
    const int r0 = by * 64;   // K dim (1024)
    #pragma unroll
    for (int i = 0; i < 4; i++) {
        int e = t + 256 * i;
        int r = e >> 4, c4 = (e & 15) * 4;
        float4 v = *(const float4*)(W + (r0 + r) * cols + c0 + c4);
        bf16x4 o = { (__bf16)v.x, (__bf16)v.y, (__bf16)v.z, (__bf16)v.w };
        *(bf16x4*)&tl[r][c4] = o;
    }
    __syncthreads();
    #pragma unroll
    for (int i = 0; i < 4; i++) {
        int e = t + 256 * i;
        int n = e >> 4, k4 = (e & 15) * 4;
        bf16x4 o = { tl[k4][n], tl[k4 + 1][n], tl[k4 + 2][n], tl[k4 + 3][n] };
        *(bf16x4*)(Wt + (c0 + n) * 1024 + r0 + k4) = o;
    }
}

// ---------------------------------------------------------------------------
// MFMA GEMM core v17 (unchanged from R13): BK=32, triple-buffered LDS,
// counted vmcnt, ONE s_barrier per K-step, slot-XOR swizzle.
// ---------------------------------------------------------------------------
template<int BM>
__device__ __forceinline__
void gemm_core_tb(__bf16* sbuf,
                  const __bf16* __restrict__ A, const __bf16* __restrict__ Bt,
                  int m0, int n0, int wm, int wn, int quad, int l16, int t,
                  f32x4 (&acc)[4][4])
{
    constexpr int MT   = BM / 32;            // m-subtiles per wave
    constexpr int AG   = BM / 64;            // A gll16s per wave (16 rows each)
    constexpr int STEP = (BM + 128) * 32;    // bf16 elems per buffer (Al+Bl)

    const int wave = t >> 6;
    const int lane = t & 63;
    const int srow = lane >> 2;                      // 0..15
    const int scol = ((lane & 3) ^ (srow & 3)) * 8;  // permuted 16B slot

    const __bf16* Ag = A  + (size_t)(m0 + wave * (BM / 4) + srow) * 1024 + scol;
    const __bf16* Bg = Bt + (size_t)(n0 + wave * 32 + srow) * 1024 + scol;

    // prologue: K-step 0 into buf 0
    {
        __bf16* Alp = sbuf;
        __bf16* Blp = sbuf + BM * 32;
        #pragma unroll
        for (int g = 0; g < AG; g++)
            gll16(Ag + (size_t)g * 16 * 1024, &Alp[(wave * (BM / 4) + g * 16) * 32]);
        gll16(Bg,                      &Blp[(wave * 32) * 32]);
        gll16(Bg + (size_t)16 * 1024,  &Blp[(wave * 32 + 16) * 32]);
    }

    const int cb = (quad ^ (l16 & 3)) * 16;          // read-side XOR byte col

    for (int j = 0; j < 32; j++) {
        const int p = j % 3;
        if (j < 31) {
            const int pn = (j + 1) % 3;
            const int k1 = (j + 1) * 32;
            __bf16* Alp = sbuf + pn * STEP;
            __bf16* Blp = Alp + BM * 32;
            #pragma unroll
            for (int g = 0; g < AG; g++)
                gll16(Ag + k1 + (size_t)g * 16 * 1024,
                      &Alp[(wave * (BM / 4) + g * 16) * 32]);
            gll16(Bg + k1,                     &Blp[(wave * 32) * 32]);
            gll16(Bg + k1 + (size_t)16 * 1024, &Blp[(wave * 32 + 16) * 32]);
            // step j's loads (issued last iter) done; j+1's stay in flight
            if constexpr (AG == 2) asm volatile("s_waitcnt vmcnt(4)" ::: "memory");
            else                   asm volatile("s_waitcnt vmcnt(3)" ::: "memory");
        } else {
            asm volatile("s_waitcnt vmcnt(0)" ::: "memory");
        }
        __builtin_amdgcn_s_barrier();          // all waves: step j in LDS
        __builtin_amdgcn_sched_barrier(0);     // pin ds_reads below barrier

        const char* Alp = (const char*)(sbuf + p * STEP);
        const char* Blp = (const char*)(sbuf + p * STEP + BM * 32);
        bf16x8 af[MT], bfr[4];
        #pragma unroll
        for (int mt = 0; mt < MT; mt++)
            af[mt] = *(const bf16x8*)(Alp + (wm * (BM / 2) + mt * 16 + l16) * 64 + cb);
        #pragma unroll
        for (int nt = 0; nt < 4; nt++)
            bfr[nt] = *(const bf16x8*)(Blp + (wn * 64 + nt * 16 + l16) * 64 + cb);
        #pragma unroll
        for (int mt = 0; mt < MT; mt++)
            #pragma unroll
            for (int nt = 0; nt < 4; nt++)
                acc[mt][nt] = __builtin_amdgcn_mfma_f32_16x16x32_bf16(
                    af[mt], bfr[nt], acc[mt][nt], 0, 0, 0);
        // no trailing barrier: triple-buffer gives reuse distance 3
    }
    __syncthreads();   // all waves done with staging LDS -> caller may reuse
}

// QKV: v17 core. R14 changes: (1) L2-strip block map — each XCD owns a
// 3-n-col x 32-m strip (B working set 0.75MB -> L2-locked, 32x reuse;
// concurrent A ~2.75MB -> total < 4MB L2); (2) V^T epilogue transposed via
// ebuf -> 4-lane x 32B contiguous stores per d-row (was 64 scattered 8B).
__global__ __launch_bounds__(256)
void qkv_mfma(const __bf16* __restrict__ A, const __bf16* __restrict__ Bt,
              const float* __restrict__ bias, __bf16* __restrict__ qkv)
{
    __shared__ __align__(16) __bf16 smem[3 * (128 + 128) * 32];   // 49152 B
    typedef __bf16 (*ebuf_p)[64][72];
    ebuf_p ebuf = (ebuf_p)smem;          // aliases staging (dead after core)

    const int t    = threadIdx.x;
    const int wave = t >> 6;
    const int lane = t & 63;
    const int quad = lane >> 4;
    const int l16  = lane & 15;
    const int wm   = wave >> 1, wn = wave & 1;
    const int bid  = blockIdx.x;
    const int xcd  = bid & 7;
    const int w    = bid >> 3;                   // 0..95
    const int n0 = (xcd * 3 + w % 3) * 128;      // XCD-private 3-n strip
    const int m0 = (w / 3) * 128;                // 0..31 m-tiles

    f32x4 acc[4][4];
    #pragma unroll
    for (int i = 0; i < 4; i++)
        #pragma unroll
        for (int j = 0; j < 4; j++)
            acc[i][j] = f32x4{0.f, 0.f, 0.f, 0.f};

    gemm_core_tb<128>(smem, A, Bt, m0, n0, wm, wn, quad, l16, t, acc);

    const int nw0 = n0 + wn * 64;
    const int which = nw0 >> 10;
    const int h = (nw0 & 1023) >> 6;

    if (which == 2) {
        // V^T: transpose wave's 64(tt) x 64(d) tile in ebuf, then per-d-row
        // contiguous stores (4 lanes x 32B cover each 128B d-row).
        #pragma unroll
        for (int nt = 0; nt < 4; nt++) {
            float bs = bias[nw0 + nt * 16 + l16];
            #pragma unroll
            for (int mt = 0; mt < 4; mt++)
                #pragma unroll
                for (int r = 0; r < 4; r++)
                    ebuf[wave][nt * 16 + l16][mt * 16 + quad * 4 + r] =
                        (__bf16)(acc[mt][nt][r] + bs);
        }
        // wave-private ebuf: ds_write -> ds_read ordered via lgkmcnt
        const int mbase = m0 + wm * 64;
        const int b   = mbase >> 11;
        const int tt0 = mbase & 2047;
        __bf16* vb0 = &qkv[2 * (size_t)BHTD +
                           ((size_t)(b * 16 + h) * 64) * 2048 + tt0];
        const int q4 = (lane & 3) * 16;
        #pragma unroll
        for (int p = 0; p < 4; p++) {
            const int d = 16 * p + (lane >> 2);
            const __bf16* src = &ebuf[wave][d][q4];
            __bf16* drow = vb0 + (size_t)d * 2048 + q4;
            *(bf16x8*)drow       = *(const bf16x8*)src;
            *(bf16x8*)(drow + 8) = *(const bf16x8*)(src + 8);
        }
    } else {
        // Q/K: wave-private ebuf staging, then 8x16B coalesced stores/lane.
        #pragma unroll
        for (int nt = 0; nt < 4; nt++) {
            float bs = bias[nw0 + nt * 16 + l16];
            #pragma unroll
            for (int mt = 0; mt < 4; mt++)
                #pragma unroll
                for (int r = 0; r < 4; r++)
                    ebuf[wave][mt * 16 + quad * 4 + r][nt * 16 + l16] =
                        (__bf16)(acc[mt][nt][r] + bs);
        }
        int m = m0 + wm * 64 + lane;
        int b = m >> 11;
        int tt = m & 2047;
        __bf16* dst = &qkv[which * (size_t)BHTD +
                           (((size_t)(b * 16 + h) * 2048 + tt) * 64)];
        #pragma unroll
        for (int c = 0; c < 8; c++)
            *(bf16x8*)(dst + c * 8) = *(const bf16x8*)&ebuf[wave][lane][c * 8];
    }
}

// Proj: v17 core, BM=64. R14: XCD-private n-panel map — each XCD owns one
// 128-col B panel (0.25MB, L2-locked); A streamed. Grid 512 = 8 x 64.
__global__ __launch_bounds__(256)
void proj_mfma(const __bf16* __restrict__ A, const __bf16* __restrict__ Bt,
               const float* __restrict__ bias, float* __restrict__ out)
{
    __shared__ __align__(16) __bf16 smem[3 * (64 + 128) * 32];    // 36864 B

    const int t    = threadIdx.x;
    const int wave = t >> 6;
    const int lane = t & 63;
    const int quad = lane >> 4;
    const int l16  = lane & 15;
    const int wm   = wave >> 1, wn = wave & 1;
    const int bid  = blockIdx.x;
    const int n0 = (bid & 7) * 128;              // XCD-private n-panel
    const int m0 = (bid >> 3) * 64;              // 0..63 m-tiles

    f32x4 acc[4][4];
    #pragma unroll
    for (int i = 0; i < 4; i++)
        #pragma unroll
        for (int j = 0; j < 4; j++)
            acc[i][j] = f32x4{0.f, 0.f, 0.f, 0.f};

    gemm_core_tb<64>(smem, A, Bt, m0, n0, wm, wn, quad, l16, t, acc);

    #pragma unroll
    for (int nt = 0; nt < 4; nt++) {
        int n = n0 + wn * 64 + nt * 16 + l16;
        float bs = bias[n];
        #pragma unroll
        for (int mt = 0; mt < 2; mt++) {
            #pragma unroll
            for (int r = 0; r < 4; r++) {
                int m = m0 + wm * 32 + mt * 16 + quad * 4 + r;
                out[m * 1024 + n] = acc[mt][nt][r] + bs;
            }
        }
    }
}

// ---------------------------------------------------------------------------
// MFMA flash attention v7 (benched 44.6us, unchanged): K-split, 8 waves,
// grid 256, triple-buffered LDS, counted vmcnt(4), one s_barrier/chunk,
// setprio around MFMA, in-register softmax via cvt_pk + permlane32_swap.
// ---------------------------------------------------------------------------
__global__ __launch_bounds__(512, 2)
void attn_mfma(const __bf16* __restrict__ Q, const __bf16* __restrict__ K,
               const __bf16* __restrict__ VT, __bf16* __restrict__ O)
{
    __shared__ __bf16 sK[2][3][64 * 64];   // [kh][buf][k_local*64+d] swizzled
    __shared__ __bf16 sV[2][3][64 * 64];   // [kh][buf][d*64+k_local] swizzled
    __shared__ float  slsum[4][2][64];     // [qg][qs][lane] kh=1 partials

    const int t    = threadIdx.x;
    const int wave = t >> 6;
    const int lane = t & 63;
    const int qg   = wave & 3;             // q-group 0..3
    const int kh   = wave >> 2;            // k-half 0..1
    const int c    = lane & 31;
    const int hi   = lane >> 5;
    const int hx   = hi * 16;              // byte offset of the 8-elem half
    const int sw   = (c & 7) << 4;         // read-side XOR swizzle

    const int blk = blockIdx.x;
    const int bh  = blk & 31;
    const int qc  = blk >> 5;              // 0..7
    const int q0  = qc * 256 + qg * 64;

    const __bf16* Qp = Q  + ((size_t)bh * Ts + q0) * Dh;
    const __bf16* Kp = K  + (size_t)bh * Ts * Dh;
    const __bf16* Vp = VT + (size_t)bh * Dh * Ts;   // [64][2048]

    // Q fragments (B-operand of mfma(K,Q)), pre-scaled by log2e/sqrt(Dh)
    const float qscale = 0.125f * 1.44269504088896f;
    bf16x8 qf[2][4];
    #pragma unroll
    for (int qs = 0; qs < 2; qs++)
        #pragma unroll
        for (int ds = 0; ds < 4; ds++) {
            bf16x8 v = *(const bf16x8*)(Qp + (qs * 32 + c) * Dh + ds * 16 + hi * 8);
            #pragma unroll
            for (int i = 0; i < 8; i++) v[i] = (__bf16)(qscale * (float)v[i]);
            qf[qs][ds] = v;
        }

    f32x16 accO[2][2];                     // [qs][dt]: O[q][dt*32+c] partial
    #pragma unroll
    for (int qs = 0; qs < 2; qs++)
        #pragma unroll
        for (int dt = 0; dt < 2; dt++)
            #pragma unroll
            for (int i = 0; i < 16; i++) accO[qs][dt][i] = 0.f;
    float lsum[2] = {0.f, 0.f};

    const f32x16 z16 = {0.f, 0.f, 0.f, 0.f, 0.f, 0.f, 0.f, 0.f,
                        0.f, 0.f, 0.f, 0.f, 0.f, 0.f, 0.f, 0.f};

    // staging: linear LDS dest (gll requirement) + permuted global source col
    const int r0 = qg * 8 + (lane >> 3);             // rows 0..31 per kh-half
    const int s8 = ((lane & 7) ^ (r0 & 7)) * 8;      // permuted col (elems)
    const __bf16* kg0 = Kp + (size_t)(kh * 1024 + r0) * Dh + s8;
    const __bf16* kg1 = kg0 + 32 * Dh;               // (32+r0)&7 == r0&7
    const __bf16* vg0 = Vp + (size_t)r0 * Ts + kh * 1024 + s8;
    const __bf16* vg1 = vg0 + (size_t)32 * Ts;

    // prologue: this half's chunk 0 into buf 0
    gll16(kg0, &sK[kh][0][qg * 512]);
    gll16(kg1, &sK[kh][0][2048 + qg * 512]);
    gll16(vg0, &sV[kh][0][qg * 512]);
    gll16(vg1, &sV[kh][0][2048 + qg * 512]);

    for (int j = 0; j < 16; j++) {
        const int p = j % 3;
        if (j < 15) {
            const int pn = (j + 1) % 3;
            gll16(kg0 + (j + 1) * 4096, &sK[kh][pn][qg * 512]);
            gll16(kg1 + (j + 1) * 4096, &sK[kh][pn][2048 + qg * 512]);
            gll16(vg0 + (j + 1) * 64,   &sV[kh][pn][qg * 512]);
            gll16(vg1 + (j + 1) * 64,   &sV[kh][pn][2048 + qg * 512]);
            // chunk j's loads (issued last iter) done; j+1's stay in flight
            asm volatile("s_waitcnt vmcnt(4)" ::: "memory");
        } else {
            asm volatile("s_waitcnt vmcnt(0)" ::: "memory");
        }
        __builtin_amdgcn_s_barrier();          // all waves: chunk j in LDS
        __builtin_amdgcn_sched_barrier(0);     // pin ds_reads below barrier

        const char* kb = (const char*)&sK[kh][p][0];
        const char* vb = (const char*)&sV[kh][p][0];

        // K fragments (A-operand): kf[kt][ds] = K[kt*32+c][ds*16+hi*8 ..+8]
        bf16x8 kf[2][4];
        #pragma unroll
        for (int kt = 0; kt < 2; kt++) {
            const char* rbase = kb + (kt * 32 + c) * 128;
            #pragma unroll
            for (int ds = 0; ds < 4; ds++)
                kf[kt][ds] = *(const bf16x8*)(rbase + ((ds * 32 + hx) ^ sw));
        }

        // QK^T: st[qs][kt] = S^T[k = kt*32 + row][q = qs*32 + c] (log2e-scaled)
        f32x16 st[2][2];
        __builtin_amdgcn_s_setprio(1);
        #pragma unroll
        for (int kt = 0; kt < 2; kt++)
            #pragma unroll
            for (int qs = 0; qs < 2; qs++)
                st[qs][kt] = __builtin_amdgcn_mfma_f32_32x32x16_bf16(
                    kf[kt][0], qf[qs][0], z16, 0, 0, 0);
        #pragma unroll
        for (int ds = 1; ds < 4; ds++)
            #pragma unroll
            for (int kt = 0; kt < 2; kt++)
                #pragma unroll
                for (int qs = 0; qs < 2; qs++)
                    st[qs][kt] = __builtin_amdgcn_mfma_f32_32x32x16_bf16(
                        kf[kt][ds], qf[qs][ds], st[qs][kt], 0, 0, 0);
        __builtin_amdgcn_s_setprio(0);

        // p = exp2(s); pack to bf16 pairs; permlane32_swap builds PV A-frags.
        bf16x8 pa[2][4];
        #pragma unroll
        for (int qs = 0; qs < 2; qs++) {
            unsigned pk[2][8];
            #pragma unroll
            for (int kt = 0; kt < 2; kt++) {
                float sum0 = 0.f, sum1 = 0.f;
                #pragma unroll
                for (int r = 0; r < 16; r++) {
                    float pv = __builtin_amdgcn_exp2f(st[qs][kt][r]);
                    st[qs][kt][r] = pv;
                    if (r & 1) sum1 += pv; else sum0 += pv;
                }
                lsum[qs] += sum0 + sum1;
                #pragma unroll
                for (int r2 = 0; r2 < 8; r2++) {
                    unsigned d;
                    asm("v_cvt_pk_bf16_f32 %0, %1, %2"
                        : "=v"(d)
                        : "v"(st[qs][kt][2 * r2]), "v"(st[qs][kt][2 * r2 + 1]));
                    pk[kt][r2] = d;
                }
            }
            #pragma unroll
            for (int s = 0; s < 4; s++) {
                const int kt = s >> 1, r4 = (s & 1) * 4;
                unsigned x0 = pk[kt][r4 + 0], y0 = pk[kt][r4 + 2];
                unsigned x1 = pk[kt][r4 + 1], y1 = pk[kt][r4 + 3];
                asm("v_permlane32_swap_b32 %0, %1" : "+v"(x0), "+v"(y0));
                asm("v_permlane32_swap_b32 %0, %1" : "+v"(x1), "+v"(y1));
                union { unsigned u[4]; bf16x8 b; } pu;
                pu.u[0] = x0; pu.u[1] = x1; pu.u[2] = y0; pu.u[3] = y1;
                pa[qs][s] = pu.b;
            }
        }

        // PV: vf (B-operand) = V^T[dt*32+c][s*16 + hi*8 + j], shared by qs
        __builtin_amdgcn_s_setprio(1);
        #pragma unroll
        for (int s = 0; s < 4; s++)
            #pragma unroll
            for (int dt = 0; dt < 2; dt++) {
                bf16x8 vf = *(const bf16x8*)(vb + (dt * 32 + c) * 128 +
                                             ((s * 32 + hx) ^ sw));
                #pragma unroll
                for (int qs = 0; qs < 2; qs++)
                    accO[qs][dt] = __builtin_amdgcn_mfma_f32_32x32x16_bf16(
                        pa[qs][s], vf, accO[qs][dt], 0, 0, 0);
            }
        __builtin_amdgcn_s_setprio(0);
        // no trailing barrier: triple-buffer guarantees buf reuse distance 3
    }

    __syncthreads();   // all compute done; staging LDS now dead -> reuse

    // cross-half reduction: kh=1 publishes partials into (dead) staging LDS,
    // kh=0 adds and runs the epilogue. Lane-consecutive f32 -> conflict-free.
    float* pb = (qg < 2) ? (float*)&sK[0][0][0] + qg * 4096
                         : (float*)&sV[0][0][0] + (qg - 2) * 4096;
    if (kh == 1) {
        #pragma unroll
        for (int qs = 0; qs < 2; qs++) {
            #pragma unroll
            for (int dt = 0; dt < 2; dt++)
                #pragma unroll
                for (int r = 0; r < 16; r++)
                    pb[((qs * 2 + dt) << 10) + (r << 6) + lane] = accO[qs][dt][r];
            slsum[qg][qs][lane] = lsum[qs];
        }
    }
    __syncthreads();
    if (kh == 0) {
        #pragma unroll
        for (int qs = 0; qs < 2; qs++) {
            #pragma unroll
            for (int dt = 0; dt < 2; dt++)
                #pragma unroll
                for (int r = 0; r < 16; r++)
                    accO[qs][dt][r] += pb[((qs * 2 + dt) << 10) + (r << 6) + lane];
            lsum[qs] += slsum[qg][qs][lane];
        }

        // epilogue: fold lsum halves, divide, store [B,T,C]
        const int b = bh >> 4, h = bh & 15;
        #pragma unroll
        for (int qs = 0; qs < 2; qs++) {
            float l = lsum[qs] + __shfl_xor(lsum[qs], 32);
            float linv = 1.f / l;
            #pragma unroll
            for (int r = 0; r < 16; r++) {
                const int qrow = (r & 3) + 8 * (r >> 2) + 4 * hi;
                float inv = __shfl(linv, qrow);
                __bf16* Op = O + ((size_t)(b * Ts + q0 + qs * 32 + qrow)) * Cc +
                             h * 64 + c;
                Op[0]  = (__bf16)(accO[qs][0][r] * inv);
                Op[32] = (__bf16)(accO[qs][1][r] * inv);
            }
        }
    }
}

// ---------------------------------------------------------------------------
extern "C" void kernel_launch(void* const* d_in, const int* in_sizes, int n_in,
                              void* d_out, int out_size, void* d_ws, size_t ws_size,
                              hipStream_t stream)
{
    (void)in_sizes; (void)n_in; (void)out_size; (void)ws_size;
    const float* x     = (const float*)d_in[0];
    const float* Wqkv  = (const float*)d_in[1];
    const float* bqkv  = (const float*)d_in[2];
    const float* Wproj = (const float*)d_in[3];
    const float* bproj = (const float*)d_in[4];
    float* out = (float*)d_out;

    __bf16* ws   = (__bf16*)d_ws;
    __bf16* Qw   = ws;                          // Q,K [B,H,T,Dh]; V^T [B,H,Dh,T]
    __bf16* XbAO = ws + 3 * (size_t)BHTD;       // Xb then AO (union)  8 MB
    __bf16* Wqt  = XbAO + (size_t)Mm * Cc;      // [3072][1024]        6 MB
    __bf16* Wpt  = Wqt + (size_t)Nqkv * Cc;     // [1024][1024]        2 MB

    prep_all<<<dim3(5120), 256, 0, stream>>>(x, XbAO, Wqkv, Wqt, Wproj, Wpt);
    qkv_mfma<<<dim3(768), 256, 0, stream>>>(XbAO, Wqt, bqkv, Qw);
    attn_mfma<<<dim3(256), 512, 0, stream>>>(
        Qw, Qw + BHTD, Qw + 2 * (size_t)BHTD, XbAO);   // AO overwrites Xb (dead)
    proj_mfma<<<dim3(512), 256, 0, stream>>>(XbAO, Wpt, bproj, out);
}

// Round 15
// 177.843 us; speedup vs baseline: 1.0346x; 1.0346x over previous
//
#include <hip/hip_runtime.h>
#include <hip/hip_bf16.h>
#include <math.h>

using bf16 = __hip_bfloat16;

typedef __bf16 bf16x8 __attribute__((ext_vector_type(8)));
typedef __bf16 bf16x4 __attribute__((ext_vector_type(4)));
typedef float  f32x4  __attribute__((ext_vector_type(4)));
typedef float  f32x16 __attribute__((ext_vector_type(16)));

constexpr int Bb = 2;
constexpr int Ts = 2048;
constexpr int Cc = 1024;
constexpr int Hh = 16;
constexpr int Dh = 64;
constexpr int Mm = Bb * Ts;        // 4096 rows of x
constexpr int Nqkv = 3 * Cc;       // 3072
constexpr int BHTD = Bb * Hh * Ts * Dh;  // elements per Q/K/V tensor

// async global->LDS, 16B per lane; LDS dest = wave-uniform base + lane*16
__device__ __forceinline__
void gll16(const __bf16* g, __bf16* l)
{
    __builtin_amdgcn_global_load_lds(
        (const __attribute__((address_space(1))) unsigned int*)g,
        (__attribute__((address_space(3))) unsigned int*)l,
        16, 0, 0);
}

// ---------------------------------------------------------------------------
// Merged prep: [0,4096) cvt X fp32->bf16; [4096,4864) transpose W_qkv;
// [4864,5120) transpose W_proj.   (benched, unchanged)
// ---------------------------------------------------------------------------
__global__ __launch_bounds__(256)
void prep_all(const float* __restrict__ x, __bf16* __restrict__ Xb,
              const float* __restrict__ Wq, __bf16* __restrict__ Wqt,
              const float* __restrict__ Wp, __bf16* __restrict__ Wpt)
{
    __shared__ __bf16 tl[64][72];
    const int bid = blockIdx.x;
    const int t = threadIdx.x;

    if (bid < 4096) {
        int i = (bid * 256 + t) * 4;
        float4 v = *(const float4*)(x + i);
        bf16x4 o = { (__bf16)v.x, (__bf16)v.y, (__bf16)v.z, (__bf16)v.w };
        *(bf16x4*)(Xb + i) = o;
        return;
    }
    const float* W; __bf16* Wt; int cols, bx, by;
    if (bid < 4096 + 768) {
        W = Wq; Wt = Wqt; cols = Nqkv;
        bx = (bid - 4096) % 48; by = (bid - 4096) / 48;
    } else {
        W = Wp; Wt = Wpt; cols = Cc;
        bx = (bid - 4864) % 16; by = (bid - 4864) / 16;
    }
    const int c0 = bx * 64;   // N dim
    const int r0 = by * 64;   // K dim (1024)
    #pragma unroll
    for (int i = 0; i < 4; i++) {
        int e = t + 256 * i;
        int r = e >> 4, c4 = (e & 15) * 4;
        float4 v = *(const float4*)(W + (r0 + r) * cols + c0 + c4);
        bf16x4 o = { (__bf16)v.x, (__bf16)v.y, (__bf16)v.z, (__bf16)v.w };
        *(bf16x4*)&tl[r][c4] = o;
    }
    __syncthreads();
    #pragma unroll
    for (int i = 0; i < 4; i++) {
        int e = t + 256 * i;
        int n = e >> 4, k4 = (e & 15) * 4;
        bf16x4 o = { tl[k4][n], tl[k4 + 1][n], tl[k4 + 2][n], tl[k4 + 3][n] };
        *(bf16x4*)(Wt + (c0 + n) * 1024 + r0 + k4) = o;
    }
}

// ---------------------------------------------------------------------------
// MFMA GEMM core v17 (proj only): BK=32, triple-buffered LDS, counted vmcnt,
// one s_barrier per K-step, slot-XOR swizzle.
// ---------------------------------------------------------------------------
template<int BM>
__device__ __forceinline__
void gemm_core_tb(__bf16* sbuf,
                  const __bf16* __restrict__ A, const __bf16* __restrict__ Bt,
                  int m0, int n0, int wm, int wn, int quad, int l16, int t,
                  f32x4 (&acc)[4][4])
{
    constexpr int MT   = BM / 32;            // m-subtiles per wave
    constexpr int AG   = BM / 64;            // A gll16s per wave (16 rows each)
    constexpr int STEP = (BM + 128) * 32;    // bf16 elems per buffer (Al+Bl)

    const int wave = t >> 6;
    const int lane = t & 63;
    const int srow = lane >> 2;                      // 0..15
    const int scol = ((lane & 3) ^ (srow & 3)) * 8;  // permuted 16B slot

    const __bf16* Ag = A  + (size_t)(m0 + wave * (BM / 4) + srow) * 1024 + scol;
    const __bf16* Bg = Bt + (size_t)(n0 + wave * 32 + srow) * 1024 + scol;

    // prologue: K-step 0 into buf 0
    {
        __bf16* Alp = sbuf;
        __bf16* Blp = sbuf + BM * 32;
        #pragma unroll
        for (int g = 0; g < AG; g++)
            gll16(Ag + (size_t)g * 16 * 1024, &Alp[(wave * (BM / 4) + g * 16) * 32]);
        gll16(Bg,                      &Blp[(wave * 32) * 32]);
        gll16(Bg + (size_t)16 * 1024,  &Blp[(wave * 32 + 16) * 32]);
    }

    const int cb = (quad ^ (l16 & 3)) * 16;          // read-side XOR byte col

    for (int j = 0; j < 32; j++) {
        const int p = j % 3;
        if (j < 31) {
            const int pn = (j + 1) % 3;
            const int k1 = (j + 1) * 32;
            __bf16* Alp = sbuf + pn * STEP;
            __bf16* Blp = Alp + BM * 32;
            #pragma unroll
            for (int g = 0; g < AG; g++)
                gll16(Ag + k1 + (size_t)g * 16 * 1024,
                      &Alp[(wave * (BM / 4) + g * 16) * 32]);
            gll16(Bg + k1,                     &Blp[(wave * 32) * 32]);
            gll16(Bg + k1 + (size_t)16 * 1024, &Blp[(wave * 32 + 16) * 32]);
            if constexpr (AG == 2) asm volatile("s_waitcnt vmcnt(4)" ::: "memory");
            else                   asm volatile("s_waitcnt vmcnt(3)" ::: "memory");
        } else {
            asm volatile("s_waitcnt vmcnt(0)" ::: "memory");
        }
        __builtin_amdgcn_s_barrier();
        __builtin_amdgcn_sched_barrier(0);

        const char* Alp = (const char*)(sbuf + p * STEP);
        const char* Blp = (const char*)(sbuf + p * STEP + BM * 32);
        bf16x8 af[MT], bfr[4];
        #pragma unroll
        for (int mt = 0; mt < MT; mt++)
            af[mt] = *(const bf16x8*)(Alp + (wm * (BM / 2) + mt * 16 + l16) * 64 + cb);
        #pragma unroll
        for (int nt = 0; nt < 4; nt++)
            bfr[nt] = *(const bf16x8*)(Blp + (wn * 64 + nt * 16 + l16) * 64 + cb);
        #pragma unroll
        for (int mt = 0; mt < MT; mt++)
            #pragma unroll
            for (int nt = 0; nt < 4; nt++)
                acc[mt][nt] = __builtin_amdgcn_mfma_f32_16x16x32_bf16(
                    af[mt], bfr[nt], acc[mt][nt], 0, 0, 0);
    }
    __syncthreads();   // all waves done with staging LDS -> caller may reuse
}

// ---------------------------------------------------------------------------
// QKV v19: 256x256 tile, BK=64, 8 waves (2M x 4N), per-wave 128x64 output.
// LDS-read-pipe theory: 128-tile core spends 3x more LDS-read cycles than
// MFMA cycles; 256-tile halves reads/MFMA and BK=64 (128B rows, r&7 XOR
// swizzle) makes frag reads 2-way (free). Schedule = v9-proven dbuf:
// vmcnt(0) [own 8 loads issued a full step ago] -> s_barrier [all loads
// landed; prior readers of other buf done] -> stage j+1 -> reads -> MFMA.
// LDS 2 x (256+256) x 64 x 2B = 128 KiB (1 block/CU). Grid 192 = 16m x 12n,
// bijective XCD swizzle (192 = 8 x 24). launch_bounds(512,2) caps VGPR 256.
// ---------------------------------------------------------------------------
__global__ __launch_bounds__(512, 2)
void qkv_mfma(const __bf16* __restrict__ A, const __bf16* __restrict__ Bt,
              const float* __restrict__ bias, __bf16* __restrict__ qkv)
{
    __shared__ __align__(16) __bf16 smem[2 * 512 * 64];   // 131072 B
    typedef __bf16 (*ebuf_p)[64][72];
    ebuf_p ebuf = (ebuf_p)smem;          // aliases staging (dead after core)

    const int t    = threadIdx.x;
    const int wave = t >> 6;             // 0..7
    const int lane = t & 63;
    const int quad = lane >> 4;
    const int l16  = lane & 15;
    const int wm   = wave >> 2;          // 0..1 (128 m-rows each)
    const int wn   = wave & 3;           // 0..3 (64 n-cols each)
    const int bid  = blockIdx.x;
    const int swb  = (bid & 7) * 24 + (bid >> 3);   // 192 = 8 x 24, bijective
    const int n0 = (swb % 12) * 256;
    const int m0 = (swb / 12) * 256;

    f32x4 acc[8][4];
    #pragma unroll
    for (int i = 0; i < 8; i++)
        #pragma unroll
        for (int j = 0; j < 4; j++)
            acc[i][j] = f32x4{0.f, 0.f, 0.f, 0.f};

    // staging: per gll, lane -> row base+(lane>>3), permuted 16B slot
    // (lane&7)^((lane>>3)&7)  => LDS[r][s] = global[r][s ^ (r&7)]
    const int srow = lane >> 3;                       // 0..7
    const int scol = ((lane & 7) ^ srow) * 8;         // permuted col (elems)
    const __bf16* Ag = A  + (size_t)(m0 + wave * 32 + srow) * 1024 + scol;
    const __bf16* Bg = Bt + (size_t)(n0 + wave * 32 + srow) * 1024 + scol;

    // prologue: K-step 0 into buf 0 (A rows 0..255 then B rows 0..255)
    {
        __bf16* Alp = smem;
        __bf16* Blp = smem + 256 * 64;
        #pragma unroll
        for (int g = 0; g < 4; g++) {
            gll16(Ag + (size_t)g * 8 * 1024, &Alp[(wave * 32 + g * 8) * 64]);
            gll16(Bg + (size_t)g * 8 * 1024, &Blp[(wave * 32 + g * 8) * 64]);
        }
    }

    for (int j = 0; j < 16; j++) {
        const int p = j & 1;
        // own step-j loads (issued a full step of compute ago) landed:
        asm volatile("s_waitcnt vmcnt(0)" ::: "memory");
        __builtin_amdgcn_s_barrier();          // all loads in LDS; prior
                                               // readers of buf p^1 done
        __builtin_amdgcn_sched_barrier(0);
        if (j < 15) {
            const int k1 = (j + 1) * 64;
            __bf16* Alp = smem + (p ^ 1) * (512 * 64);
            __bf16* Blp = Alp + 256 * 64;
            #pragma unroll
            for (int g = 0; g < 4; g++) {
                gll16(Ag + k1 + (size_t)g * 8 * 1024, &Alp[(wave * 32 + g * 8) * 64]);
                gll16(Bg + k1 + (size_t)g * 8 * 1024, &Blp[(wave * 32 + g * 8) * 64]);
            }
        }
        const char* Alp = (const char*)(smem + p * (512 * 64));
        const char* Blp = Alp + 256 * 64 * 2;   // +32768 bytes

        #pragma unroll
        for (int kk = 0; kk < 2; kk++) {
            const int cb = ((kk * 4 + quad) ^ (l16 & 7)) * 16;  // swz byte col
            bf16x8 af[8], bfr[4];
            #pragma unroll
            for (int mt = 0; mt < 8; mt++)
                af[mt] = *(const bf16x8*)(Alp + (wm * 128 + mt * 16 + l16) * 128 + cb);
            #pragma unroll
            for (int nt = 0; nt < 4; nt++)
                bfr[nt] = *(const bf16x8*)(Blp + (wn * 64 + nt * 16 + l16) * 128 + cb);
            __builtin_amdgcn_s_setprio(1);
            #pragma unroll
            for (int mt = 0; mt < 8; mt++)
                #pragma unroll
                for (int nt = 0; nt < 4; nt++)
                    acc[mt][nt] = __builtin_amdgcn_mfma_f32_16x16x32_bf16(
                        af[mt], bfr[nt], acc[mt][nt], 0, 0, 0);
            __builtin_amdgcn_s_setprio(0);
        }
    }
    __syncthreads();   // staging LDS dead -> ebuf reuse

    // epilogue: wave's 128(m) x 64(n) tile in two 64-row halves.
    const int nw0 = n0 + wn * 64;
    const int which = nw0 >> 10;
    const int h = (nw0 & 1023) >> 6;

    #pragma unroll
    for (int hh = 0; hh < 2; hh++) {
        if (which == 2) {
            // V^T: transpose 64(tt) x 64(d) in ebuf, contiguous d-row stores
            #pragma unroll
            for (int nt = 0; nt < 4; nt++) {
                float bs = bias[nw0 + nt * 16 + l16];
                #pragma unroll
                for (int ml = 0; ml < 4; ml++) {
                    const int mt = hh * 4 + ml;
                    #pragma unroll
                    for (int r = 0; r < 4; r++)
                        ebuf[wave][nt * 16 + l16][ml * 16 + quad * 4 + r] =
                            (__bf16)(acc[mt][nt][r] + bs);
                }
            }
            const int mbase = m0 + wm * 128 + hh * 64;
            const int b   = mbase >> 11;
            const int tt0 = mbase & 2047;
            __bf16* vb0 = &qkv[2 * (size_t)BHTD +
                               ((size_t)(b * 16 + h) * 64) * 2048 + tt0];
            const int q4 = (lane & 3) * 16;
            #pragma unroll
            for (int p2 = 0; p2 < 4; p2++) {
                const int d = 16 * p2 + (lane >> 2);
                const __bf16* src = &ebuf[wave][d][q4];
                __bf16* drow = vb0 + (size_t)d * 2048 + q4;
                *(bf16x8*)drow       = *(const bf16x8*)src;
                *(bf16x8*)(drow + 8) = *(const bf16x8*)(src + 8);
            }
        } else {
            // Q/K: ebuf staging, then 8x16B coalesced stores per lane
            #pragma unroll
            for (int nt = 0; nt < 4; nt++) {
                float bs = bias[nw0 + nt * 16 + l16];
                #pragma unroll
                for (int ml = 0; ml < 4; ml++) {
                    const int mt = hh * 4 + ml;
                    #pragma unroll
                    for (int r = 0; r < 4; r++)
                        ebuf[wave][ml * 16 + quad * 4 + r][nt * 16 + l16] =
                            (__bf16)(acc[mt][nt][r] + bs);
                }
            }
            int m = m0 + wm * 128 + hh * 64 + lane;
            int b = m >> 11;
            int tt = m & 2047;
            __bf16* dst = &qkv[which * (size_t)BHTD +
                               (((size_t)(b * 16 + h) * 2048 + tt) * 64)];
            #pragma unroll
            for (int c = 0; c < 8; c++)
                *(bf16x8*)(dst + c * 8) = *(const bf16x8*)&ebuf[wave][lane][c * 8];
        }
    }
}

// Proj: v17 core, BM=64. XCD-private n-panel map. Grid 512 = 8 x 64.
__global__ __launch_bounds__(256)
void proj_mfma(const __bf16* __restrict__ A, const __bf16* __restrict__ Bt,
               const float* __restrict__ bias, float* __restrict__ out)
{
    __shared__ __align__(16) __bf16 smem[3 * (64 + 128) * 32];    // 36864 B

    const int t    = threadIdx.x;
    const int wave = t >> 6;
    const int lane = t & 63;
    const int quad = lane >> 4;
    const int l16  = lane & 15;
    const int wm   = wave >> 1, wn = wave & 1;
    const int bid  = blockIdx.x;
    const int n0 = (bid & 7) * 128;              // XCD-private n-panel
    const int m0 = (bid >> 3) * 64;              // 0..63 m-tiles

    f32x4 acc[4][4];
    #pragma unroll
    for (int i = 0; i < 4; i++)
        #pragma unroll
        for (int j = 0; j < 4; j++)
            acc[i][j] = f32x4{0.f, 0.f, 0.f, 0.f};

    gemm_core_tb<64>(smem, A, Bt, m0, n0, wm, wn, quad, l16, t, acc);

    #pragma unroll
    for (int nt = 0; nt < 4; nt++) {
        int n = n0 + wn * 64 + nt * 16 + l16;
        float bs = bias[n];
        #pragma unroll
        for (int mt = 0; mt < 2; mt++) {
            #pragma unroll
            for (int r = 0; r < 4; r++) {
                int m = m0 + wm * 32 + mt * 16 + quad * 4 + r;
                out[m * 1024 + n] = acc[mt][nt][r] + bs;
            }
        }
    }
}

// ---------------------------------------------------------------------------
// MFMA flash attention v7 (benched 44.6us, unchanged).
// ---------------------------------------------------------------------------
__global__ __launch_bounds__(512, 2)
void attn_mfma(const __bf16* __restrict__ Q, const __bf16* __restrict__ K,
               const __bf16* __restrict__ VT, __bf16* __restrict__ O)
{
    __shared__ __bf16 sK[2][3][64 * 64];   // [kh][buf][k_local*64+d] swizzled
    __shared__ __bf16 sV[2][3][64 * 64];   // [kh][buf][d*64+k_local] swizzled
    __shared__ float  slsum[4][2][64];     // [qg][qs][lane] kh=1 partials

    const int t    = threadIdx.x;
    const int wave = t >> 6;
    const int lane = t & 63;
    const int qg   = wave & 3;             // q-group 0..3
    const int kh   = wave >> 2;            // k-half 0..1
    const int c    = lane & 31;
    const int hi   = lane >> 5;
    const int hx   = hi * 16;              // byte offset of the 8-elem half
    const int sw   = (c & 7) << 4;         // read-side XOR swizzle

    const int blk = blockIdx.x;
    const int bh  = blk & 31;
    const int qc  = blk >> 5;              // 0..7
    const int q0  = qc * 256 + qg * 64;

    const __bf16* Qp = Q  + ((size_t)bh * Ts + q0) * Dh;
    const __bf16* Kp = K  + (size_t)bh * Ts * Dh;
    const __bf16* Vp = VT + (size_t)bh * Dh * Ts;   // [64][2048]

    // Q fragments (B-operand of mfma(K,Q)), pre-scaled by log2e/sqrt(Dh)
    const float qscale = 0.125f * 1.44269504088896f;
    bf16x8 qf[2][4];
    #pragma unroll
    for (int qs = 0; qs < 2; qs++)
        #pragma unroll
        for (int ds = 0; ds < 4; ds++) {
            bf16x8 v = *(const bf16x8*)(Qp + (qs * 32 + c) * Dh + ds * 16 + hi * 8);
            #pragma unroll
            for (int i = 0; i < 8; i++) v[i] = (__bf16)(qscale * (float)v[i]);
            qf[qs][ds] = v;
        }

    f32x16 accO[2][2];                     // [qs][dt]: O[q][dt*32+c] partial
    #pragma unroll
    for (int qs = 0; qs < 2; qs++)
        #pragma unroll
        for (int dt = 0; dt < 2; dt++)
            #pragma unroll
            for (int i = 0; i < 16; i++) accO[qs][dt][i] = 0.f;
    float lsum[2] = {0.f, 0.f};

    const f32x16 z16 = {0.f, 0.f, 0.f, 0.f, 0.f, 0.f, 0.f, 0.f,
                        0.f, 0.f, 0.f, 0.f, 0.f, 0.f, 0.f, 0.f};

    // staging: linear LDS dest (gll requirement) + permuted global source col
    const int r0 = qg * 8 + (lane >> 3);             // rows 0..31 per kh-half
    const int s8 = ((lane & 7) ^ (r0 & 7)) * 8;      // permuted col (elems)
    const __bf16* kg0 = Kp + (size_t)(kh * 1024 + r0) * Dh + s8;
    const __bf16* kg1 = kg0 + 32 * Dh;               // (32+r0)&7 == r0&7
    const __bf16* vg0 = Vp + (size_t)r0 * Ts + kh * 1024 + s8;
    const __bf16* vg1 = vg0 + (size_t)32 * Ts;

    // prologue: this half's chunk 0 into buf 0
    gll16(kg0, &sK[kh][0][qg * 512]);
    gll16(kg1, &sK[kh][0][2048 + qg * 512]);
    gll16(vg0, &sV[kh][0][qg * 512]);
    gll16(vg1, &sV[kh][0][2048 + qg * 512]);

    for (int j = 0; j < 16; j++) {
        const int p = j % 3;
        if (j < 15) {
            const int pn = (j + 1) % 3;
            gll16(kg0 + (j + 1) * 4096, &sK[kh][pn][qg * 512]);
            gll16(kg1 + (j + 1) * 4096, &sK[kh][pn][2048 + qg * 512]);
            gll16(vg0 + (j + 1) * 64,   &sV[kh][pn][qg * 512]);
            gll16(vg1 + (j + 1) * 64,   &sV[kh][pn][2048 + qg * 512]);
            // chunk j's loads (issued last iter) done; j+1's stay in flight
            asm volatile("s_waitcnt vmcnt(4)" ::: "memory");
        } else {
            asm volatile("s_waitcnt vmcnt(0)" ::: "memory");
        }
        __builtin_amdgcn_s_barrier();          // all waves: chunk j in LDS
        __builtin_amdgcn_sched_barrier(0);     // pin ds_reads below barrier

        const char* kb = (const char*)&sK[kh][p][0];
        const char* vb = (const char*)&sV[kh][p][0];

        // K fragments (A-operand): kf[kt][ds] = K[kt*32+c][ds*16+hi*8 ..+8]
        bf16x8 kf[2][4];
        #pragma unroll
        for (int kt = 0; kt < 2; kt++) {
            const char* rbase = kb + (kt * 32 + c) * 128;
            #pragma unroll
            for (int ds = 0; ds < 4; ds++)
                kf[kt][ds] = *(const bf16x8*)(rbase + ((ds * 32 + hx) ^ sw));
        }

        // QK^T: st[qs][kt] = S^T[k = kt*32 + row][q = qs*32 + c] (log2e-scaled)
        f32x16 st[2][2];
        __builtin_amdgcn_s_setprio(1);
        #pragma unroll
        for (int kt = 0; kt < 2; kt++)
            #pragma unroll
            for (int qs = 0; qs < 2; qs++)
                st[qs][kt] = __builtin_amdgcn_mfma_f32_32x32x16_bf16(
                    kf[kt][0], qf[qs][0], z16, 0, 0, 0);
        #pragma unroll
        for (int ds = 1; ds < 4; ds++)
            #pragma unroll
            for (int kt = 0; kt < 2; kt++)
                #pragma unroll
                for (int qs = 0; qs < 2; qs++)
                    st[qs][kt] = __builtin_amdgcn_mfma_f32_32x32x16_bf16(
                        kf[kt][ds], qf[qs][ds], st[qs][kt], 0, 0, 0);
        __builtin_amdgcn_s_setprio(0);

        // p = exp2(s); pack to bf16 pairs; permlane32_swap builds PV A-frags.
        bf16x8 pa[2][4];
        #pragma unroll
        for (int qs = 0; qs < 2; qs++) {
            unsigned pk[2][8];
            #pragma unroll
            for (int kt = 0; kt < 2; kt++) {
                float sum0 = 0.f, sum1 = 0.f;
                #pragma unroll
                for (int r = 0; r < 16; r++) {
                    float pv = __builtin_amdgcn_exp2f(st[qs][kt][r]);
                    st[qs][kt][r] = pv;
                    if (r & 1) sum1 += pv; else sum0 += pv;
                }
                lsum[qs] += sum0 + sum1;
                #pragma unroll
                for (int r2 = 0; r2 < 8; r2++) {
                    unsigned d;
                    asm("v_cvt_pk_bf16_f32 %0, %1, %2"
                        : "=v"(d)
                        : "v"(st[qs][kt][2 * r2]), "v"(st[qs][kt][2 * r2 + 1]));
                    pk[kt][r2] = d;
                }
            }
            #pragma unroll
            for (int s = 0; s < 4; s++) {
                const int kt = s >> 1, r4 = (s & 1) * 4;
                unsigned x0 = pk[kt][r4 + 0], y0 = pk[kt][r4 + 2];
                unsigned x1 = pk[kt][r4 + 1], y1 = pk[kt][r4 + 3];
                asm("v_permlane32_swap_b32 %0, %1" : "+v"(x0), "+v"(y0));
                asm("v_permlane32_swap_b32 %0, %1" : "+v"(x1), "+v"(y1));
                union { unsigned u[4]; bf16x8 b; } pu;
                pu.u[0] = x0; pu.u[1] = x1; pu.u[2] = y0; pu.u[3] = y1;
                pa[qs][s] = pu.b;
            }
        }

        // PV: vf (B-operand) = V^T[dt*32+c][s*16 + hi*8 + j], shared by qs
        __builtin_amdgcn_s_setprio(1);
        #pragma unroll
        for (int s = 0; s < 4; s++)
            #pragma unroll
            for (int dt = 0; dt < 2; dt++) {
                bf16x8 vf = *(const bf16x8*)(vb + (dt * 32 + c) * 128 +
                                             ((s * 32 + hx) ^ sw));
                #pragma unroll
                for (int qs = 0; qs < 2; qs++)
                    accO[qs][dt] = __builtin_amdgcn_mfma_f32_32x32x16_bf16(
                        pa[qs][s], vf, accO[qs][dt], 0, 0, 0);
            }
        __builtin_amdgcn_s_setprio(0);
        // no trailing barrier: triple-buffer guarantees buf reuse distance 3
    }

    __syncthreads();   // all compute done; staging LDS now dead -> reuse

    // cross-half reduction: kh=1 publishes partials into (dead) staging LDS,
    // kh=0 adds and runs the epilogue. Lane-consecutive f32 -> conflict-free.
    float* pb = (qg < 2) ? (float*)&sK[0][0][0] + qg * 4096
                         : (float*)&sV[0][0][0] + (qg - 2) * 4096;
    if (kh == 1) {
        #pragma unroll
        for (int qs = 0; qs < 2; qs++) {
            #pragma unroll
            for (int dt = 0; dt < 2; dt++)
                #pragma unroll
                for (int r = 0; r < 16; r++)
                    pb[((qs * 2 + dt) << 10) + (r << 6) + lane] = accO[qs][dt][r];
            slsum[qg][qs][lane] = lsum[qs];
        }
    }
    __syncthreads();
    if (kh == 0) {
        #pragma unroll
        for (int qs = 0; qs < 2; qs++) {
            #pragma unroll
            for (int dt = 0; dt < 2; dt++)
                #pragma unroll
                for (int r = 0; r < 16; r++)
                    accO[qs][dt][r] += pb[((qs * 2 + dt) << 10) + (r << 6) + lane];
            lsum[qs] += slsum[qg][qs][lane];
        }

        // epilogue: fold lsum halves, divide, store [B,T,C]
        const int b = bh >> 4, h = bh & 15;
        #pragma unroll
        for (int qs = 0; qs < 2; qs++) {
            float l = lsum[qs] + __shfl_xor(lsum[qs], 32);
            float linv = 1.f / l;
            #pragma unroll
            for (int r = 0; r < 16; r++) {
                const int qrow = (r & 3) + 8 * (r >> 2) + 4 * hi;
                float inv = __shfl(linv, qrow);
                __bf16* Op = O + ((size_t)(b * Ts + q0 + qs * 32 + qrow)) * Cc +
                             h * 64 + c;
                Op[0]  = (__bf16)(accO[qs][0][r] * inv);
                Op[32] = (__bf16)(accO[qs][1][r] * inv);
            }
        }
    }
}

// ---------------------------------------------------------------------------
extern "C" void kernel_launch(void* const* d_in, const int* in_sizes, int n_in,
                              void* d_out, int out_size, void* d_ws, size_t ws_size,
                              hipStream_t stream)
{
    (void)in_sizes; (void)n_in; (void)out_size; (void)ws_size;
    const float* x     = (const float*)d_in[0];
    const float* Wqkv  = (const float*)d_in[1];
    const float* bqkv  = (const float*)d_in[2];
    const float* Wproj = (const float*)d_in[3];
    const float* bproj = (const float*)d_in[4];
    float* out = (float*)d_out;

    __bf16* ws   = (__bf16*)d_ws;
    __bf16* Qw   = ws;                          // Q,K [B,H,T,Dh]; V^T [B,H,Dh,T]
    __bf16* XbAO = ws + 3 * (size_t)BHTD;       // Xb then AO (union)  8 MB
    __bf16* Wqt  = XbAO + (size_t)Mm * Cc;      // [3072][1024]        6 MB
    __bf16* Wpt  = Wqt + (size_t)Nqkv * Cc;     // [1024][1024]        2 MB

    prep_all<<<dim3(5120), 256, 0, stream>>>(x, XbAO, Wqkv, Wqt, Wproj, Wpt);
    qkv_mfma<<<dim3(192), 512, 0, stream>>>(XbAO, Wqt, bqkv, Qw);
    attn_mfma<<<dim3(256), 512, 0, stream>>>(
        Qw, Qw + BHTD, Qw + 2 * (size_t)BHTD, XbAO);   // AO overwrites Xb (dead)
    proj_mfma<<<dim3(512), 256, 0, stream>>>(XbAO, Wpt, bproj, out);
}

// Round 16
// 177.197 us; speedup vs baseline: 1.0384x; 1.0036x over previous
//
#include <hip/hip_runtime.h>
#include <hip/hip_bf16.h>
#include <math.h>

using bf16 = __hip_bfloat16;

typedef __bf16 bf16x8 __attribute__((ext_vector_type(8)));
typedef __bf16 bf16x4 __attribute__((ext_vector_type(4)));
typedef float  f32x4  __attribute__((ext_vector_type(4)));
typedef float  f32x16 __attribute__((ext_vector_type(16)));

constexpr int Bb = 2;
constexpr int Ts = 2048;
constexpr int Cc = 1024;
constexpr int Hh = 16;
constexpr int Dh = 64;
constexpr int Mm = Bb * Ts;        // 4096 rows of x
constexpr int Nqkv = 3 * Cc;       // 3072
constexpr int BHTD = Bb * Hh * Ts * Dh;  // elements per Q/K/V tensor

// async global->LDS, 16B per lane; LDS dest = wave-uniform base + lane*16
__device__ __forceinline__
void gll16(const __bf16* g, __bf16* l)
{
    __builtin_amdgcn_global_load_lds(
        (const __attribute__((address_space(1))) unsigned int*)g,
        (__attribute__((address_space(3))) unsigned int*)l,
        16, 0, 0);
}

// ---------------------------------------------------------------------------
// Merged prep (R16: grid 2048): [0,1024) cvt X fp32->bf16, 4 float4/thread
// grid-stride; [1024,1792) transpose W_qkv; [1792,2048) transpose W_proj.
// ---------------------------------------------------------------------------
__global__ __launch_bounds__(256)
void prep_all(const float* __restrict__ x, __bf16* __restrict__ Xb,
              const float* __restrict__ Wq, __bf16* __restrict__ Wqt,
              const float* __restrict__ Wp, __bf16* __restrict__ Wpt)
{
    __shared__ __bf16 tl[64][72];
    const int bid = blockIdx.x;
    const int t = threadIdx.x;

    if (bid < 1024) {
        #pragma unroll
        for (int s = 0; s < 4; s++) {
            int i = (bid * 256 + t + s * 262144) * 4;
            float4 v = *(const float4*)(x + i);
            bf16x4 o = { (__bf16)v.x, (__bf16)v.y, (__bf16)v.z, (__bf16)v.w };
            *(bf16x4*)(Xb + i) = o;
        }
        return;
    }
    const float* W; __bf16* Wt; int cols, bx, by;
    if (bid < 1024 + 768) {
        W = Wq; Wt = Wqt; cols = Nqkv;
        bx = (bid - 1024) % 48; by = (bid - 1024) / 48;
    } else {
        W = Wp; Wt = Wpt; cols = Cc;
        bx = (bid - 1792) % 16; by = (bid - 1792) / 16;
    }
    const int c0 = bx * 64;   // N dim
    const int r0 = by * 64;   // K dim (1024)
    #pragma unroll
    for (int i = 0; i < 4; i++) {
        int e = t + 256 * i;
        int r = e >> 4, c4 = (e & 15) * 4;
        float4 v = *(const float4*)(W + (r0 + r) * cols + c0 + c4);
        bf16x4 o = { (__bf16)v.x, (__bf16)v.y, (__bf16)v.z, (__bf16)v.w };
        *(bf16x4*)&tl[r][c4] = o;
    }
    __syncthreads();
    #pragma unroll
    for (int i = 0; i < 4; i++) {
        int e = t + 256 * i;
        int n = e >> 4, k4 = (e & 15) * 4;
        bf16x4 o = { tl[k4][n], tl[k4 + 1][n], tl[k4 + 2][n], tl[k4 + 3][n] };
        *(bf16x4*)(Wt + (c0 + n) * 1024 + r0 + k4) = o;
    }
}

// ---------------------------------------------------------------------------
// QKV v19 (R15-benched, unchanged): 256x256 tile, BK=64, 8 waves (2M x 4N),
// per-wave 128x64 output. Dbuf schedule: vmcnt(0) [own 8 loads issued a full
// step ago] -> s_barrier -> stage j+1 -> swizzled reads -> MFMA.
// LDS 128 KiB (1 block/CU). Grid 192 = 8 x 24 bijective XCD swizzle.
// ---------------------------------------------------------------------------
__global__ __launch_bounds__(512, 2)
void qkv_mfma(const __bf16* __restrict__ A, const __bf16* __restrict__ Bt,
              const float* __restrict__ bias, __bf16* __restrict__ qkv)
{
    __shared__ __align__(16) __bf16 smem[2 * 512 * 64];   // 131072 B
    typedef __bf16 (*ebuf_p)[64][72];
    ebuf_p ebuf = (ebuf_p)smem;          // aliases staging (dead after core)

    const int t    = threadIdx.x;
    const int wave = t >> 6;             // 0..7
    const int lane = t & 63;
    const int quad = lane >> 4;
    const int l16  = lane & 15;
    const int wm   = wave >> 2;          // 0..1 (128 m-rows each)
    const int wn   = wave & 3;           // 0..3 (64 n-cols each)
    const int bid  = blockIdx.x;
    const int swb  = (bid & 7) * 24 + (bid >> 3);   // 192 = 8 x 24, bijective
    const int n0 = (swb % 12) * 256;
    const int m0 = (swb / 12) * 256;

    f32x4 acc[8][4];
    #pragma unroll
    for (int i = 0; i < 8; i++)
        #pragma unroll
        for (int j = 0; j < 4; j++)
            acc[i][j] = f32x4{0.f, 0.f, 0.f, 0.f};

    const int srow = lane >> 3;                       // 0..7
    const int scol = ((lane & 7) ^ srow) * 8;         // permuted col (elems)
    const __bf16* Ag = A  + (size_t)(m0 + wave * 32 + srow) * 1024 + scol;
    const __bf16* Bg = Bt + (size_t)(n0 + wave * 32 + srow) * 1024 + scol;

    // prologue: K-step 0 into buf 0 (A rows 0..255 then B rows 0..255)
    {
        __bf16* Alp = smem;
        __bf16* Blp = smem + 256 * 64;
        #pragma unroll
        for (int g = 0; g < 4; g++) {
            gll16(Ag + (size_t)g * 8 * 1024, &Alp[(wave * 32 + g * 8) * 64]);
            gll16(Bg + (size_t)g * 8 * 1024, &Blp[(wave * 32 + g * 8) * 64]);
        }
    }

    for (int j = 0; j < 16; j++) {
        const int p = j & 1;
        asm volatile("s_waitcnt vmcnt(0)" ::: "memory");
        __builtin_amdgcn_s_barrier();
        __builtin_amdgcn_sched_barrier(0);
        if (j < 15) {
            const int k1 = (j + 1) * 64;
            __bf16* Alp = smem + (p ^ 1) * (512 * 64);
            __bf16* Blp = Alp + 256 * 64;
            #pragma unroll
            for (int g = 0; g < 4; g++) {
                gll16(Ag + k1 + (size_t)g * 8 * 1024, &Alp[(wave * 32 + g * 8) * 64]);
                gll16(Bg + k1 + (size_t)g * 8 * 1024, &Blp[(wave * 32 + g * 8) * 64]);
            }
        }
        const char* Alp = (const char*)(smem + p * (512 * 64));
        const char* Blp = Alp + 256 * 64 * 2;   // +32768 bytes

        #pragma unroll
        for (int kk = 0; kk < 2; kk++) {
            const int cb = ((kk * 4 + quad) ^ (l16 & 7)) * 16;  // swz byte col
            bf16x8 af[8], bfr[4];
            #pragma unroll
            for (int mt = 0; mt < 8; mt++)
                af[mt] = *(const bf16x8*)(Alp + (wm * 128 + mt * 16 + l16) * 128 + cb);
            #pragma unroll
            for (int nt = 0; nt < 4; nt++)
                bfr[nt] = *(const bf16x8*)(Blp + (wn * 64 + nt * 16 + l16) * 128 + cb);
            __builtin_amdgcn_s_setprio(1);
            #pragma unroll
            for (int mt = 0; mt < 8; mt++)
                #pragma unroll
                for (int nt = 0; nt < 4; nt++)
                    acc[mt][nt] = __builtin_amdgcn_mfma_f32_16x16x32_bf16(
                        af[mt], bfr[nt], acc[mt][nt], 0, 0, 0);
            __builtin_amdgcn_s_setprio(0);
        }
    }
    __syncthreads();   // staging LDS dead -> ebuf reuse

    // epilogue: wave's 128(m) x 64(n) tile in two 64-row halves.
    const int nw0 = n0 + wn * 64;
    const int which = nw0 >> 10;
    const int h = (nw0 & 1023) >> 6;

    #pragma unroll
    for (int hh = 0; hh < 2; hh++) {
        if (which == 2) {
            // V^T: transpose 64(tt) x 64(d) in ebuf, contiguous d-row stores
            #pragma unroll
            for (int nt = 0; nt < 4; nt++) {
                float bs = bias[nw0 + nt * 16 + l16];
                #pragma unroll
                for (int ml = 0; ml < 4; ml++) {
                    const int mt = hh * 4 + ml;
                    #pragma unroll
                    for (int r = 0; r < 4; r++)
                        ebuf[wave][nt * 16 + l16][ml * 16 + quad * 4 + r] =
                            (__bf16)(acc[mt][nt][r] + bs);
                }
            }
            const int mbase = m0 + wm * 128 + hh * 64;
            const int b   = mbase >> 11;
            const int tt0 = mbase & 2047;
            __bf16* vb0 = &qkv[2 * (size_t)BHTD +
                               ((size_t)(b * 16 + h) * 64) * 2048 + tt0];
            const int q4 = (lane & 3) * 16;
            #pragma unroll
            for (int p2 = 0; p2 < 4; p2++) {
                const int d = 16 * p2 + (lane >> 2);
                const __bf16* src = &ebuf[wave][d][q4];
                __bf16* drow = vb0 + (size_t)d * 2048 + q4;
                *(bf16x8*)drow       = *(const bf16x8*)src;
                *(bf16x8*)(drow + 8) = *(const bf16x8*)(src + 8);
            }
        } else {
            // Q/K: ebuf staging, then 8x16B coalesced stores per lane
            #pragma unroll
            for (int nt = 0; nt < 4; nt++) {
                float bs = bias[nw0 + nt * 16 + l16];
                #pragma unroll
                for (int ml = 0; ml < 4; ml++) {
                    const int mt = hh * 4 + ml;
                    #pragma unroll
                    for (int r = 0; r < 4; r++)
                        ebuf[wave][ml * 16 + quad * 4 + r][nt * 16 + l16] =
                            (__bf16)(acc[mt][nt][r] + bs);
                }
            }
            int m = m0 + wm * 128 + hh * 64 + lane;
            int b = m >> 11;
            int tt = m & 2047;
            __bf16* dst = &qkv[which * (size_t)BHTD +
                               (((size_t)(b * 16 + h) * 2048 + tt) * 64)];
            #pragma unroll
            for (int c = 0; c < 8; c++)
                *(bf16x8*)(dst + c * 8) = *(const bf16x8*)&ebuf[wave][lane][c * 8];
        }
    }
}

// ---------------------------------------------------------------------------
// Proj v20: the v19 structure restricted to 4 waves / 128x128 tile, BK=64.
// Per step per wave: 4+4 gll16 staged (same 32-row pattern as qkv), 8 b128
// frag reads -> 16 MFMA (ratio 2.0 vs old BM=64/BK=32 core's 1.33); 128 B
// rows + r&7 XOR swizzle -> 2-way (free) conflicts; 16 steps (was 32).
// LDS 2 x 256 x 64 x 2B = 64 KiB -> 2 blocks/CU. Grid 256 = 8(n) x 32(m):
// each XCD owns one 128-col B panel (0.25 MB, L2-resident).
// ---------------------------------------------------------------------------
__global__ __launch_bounds__(256)
void proj_mfma(const __bf16* __restrict__ A, const __bf16* __restrict__ Bt,
               const float* __restrict__ bias, float* __restrict__ out)
{
    __shared__ __align__(16) __bf16 smem[2 * 256 * 64];   // 65536 B

    const int t    = threadIdx.x;
    const int wave = t >> 6;             // 0..3
    const int lane = t & 63;
    const int quad = lane >> 4;
    const int l16  = lane & 15;
    const int wm   = wave >> 1, wn = wave & 1;
    const int bid  = blockIdx.x;
    const int n0 = (bid & 7) * 128;      // XCD-private n-panel
    const int m0 = (bid >> 3) * 128;     // 0..31 m-tiles

    f32x4 acc[4][4];
    #pragma unroll
    for (int i = 0; i < 4; i++)
        #pragma unroll
        for (int j = 0; j < 4; j++)
            acc[i][j] = f32x4{0.f, 0.f, 0.f, 0.f};

    const int srow = lane >> 3;                       // 0..7
    const int scol = ((lane & 7) ^ srow) * 8;         // permuted col (elems)
    const __bf16* Ag = A  + (size_t)(m0 + wave * 32 + srow) * 1024 + scol;
    const __bf16* Bg = Bt + (size_t)(n0 + wave * 32 + srow) * 1024 + scol;

    // prologue: K-step 0 into buf 0 (A rows 0..127 then B rows 0..127)
    {
        __bf16* Alp = smem;
        __bf16* Blp = smem + 128 * 64;
        #pragma unroll
        for (int g = 0; g < 4; g++) {
            gll16(Ag + (size_t)g * 8 * 1024, &Alp[(wave * 32 + g * 8) * 64]);
            gll16(Bg + (size_t)g * 8 * 1024, &Blp[(wave * 32 + g * 8) * 64]);
        }
    }

    for (int j = 0; j < 16; j++) {
        const int p = j & 1;
        asm volatile("s_waitcnt vmcnt(0)" ::: "memory");
        __builtin_amdgcn_s_barrier();
        __builtin_amdgcn_sched_barrier(0);
        if (j < 15) {
            const int k1 = (j + 1) * 64;
            __bf16* Alp = smem + (p ^ 1) * (256 * 64);
            __bf16* Blp = Alp + 128 * 64;
            #pragma unroll
            for (int g = 0; g < 4; g++) {
                gll16(Ag + k1 + (size_t)g * 8 * 1024, &Alp[(wave * 32 + g * 8) * 64]);
                gll16(Bg + k1 + (size_t)g * 8 * 1024, &Blp[(wave * 32 + g * 8) * 64]);
            }
        }
        const char* Alp = (const char*)(smem + p * (256 * 64));
        const char* Blp = Alp + 128 * 64 * 2;   // +16384 bytes

        #pragma unroll
        for (int kk = 0; kk < 2; kk++) {
            const int cb = ((kk * 4 + quad) ^ (l16 & 7)) * 16;  // swz byte col
            bf16x8 af[4], bfr[4];
            #pragma unroll
            for (int mt = 0; mt < 4; mt++)
                af[mt] = *(const bf16x8*)(Alp + (wm * 64 + mt * 16 + l16) * 128 + cb);
            #pragma unroll
            for (int nt = 0; nt < 4; nt++)
                bfr[nt] = *(const bf16x8*)(Blp + (wn * 64 + nt * 16 + l16) * 128 + cb);
            __builtin_amdgcn_s_setprio(1);
            #pragma unroll
            for (int mt = 0; mt < 4; mt++)
                #pragma unroll
                for (int nt = 0; nt < 4; nt++)
                    acc[mt][nt] = __builtin_amdgcn_mfma_f32_16x16x32_bf16(
                        af[mt], bfr[nt], acc[mt][nt], 0, 0, 0);
            __builtin_amdgcn_s_setprio(0);
        }
    }

    #pragma unroll
    for (int nt = 0; nt < 4; nt++) {
        int n = n0 + wn * 64 + nt * 16 + l16;
        float bs = bias[n];
        #pragma unroll
        for (int mt = 0; mt < 4; mt++) {
            #pragma unroll
            for (int r = 0; r < 4; r++) {
                int m = m0 + wm * 64 + mt * 16 + quad * 4 + r;
                out[m * 1024 + n] = acc[mt][nt][r] + bs;
            }
        }
    }
}

// ---------------------------------------------------------------------------
// MFMA flash attention v7 (benched 44.6us, unchanged).
// ---------------------------------------------------------------------------
__global__ __launch_bounds__(512, 2)
void attn_mfma(const __bf16* __restrict__ Q, const __bf16* __restrict__ K,
               const __bf16* __restrict__ VT, __bf16* __restrict__ O)
{
    __shared__ __bf16 sK[2][3][64 * 64];   // [kh][buf][k_local*64+d] swizzled
    __shared__ __bf16 sV[2][3][64 * 64];   // [kh][buf][d*64+k_local] swizzled
    __shared__ float  slsum[4][2][64];     // [qg][qs][lane] kh=1 partials

    const int t    = threadIdx.x;
    const int wave = t >> 6;
    const int lane = t & 63;
    const int qg   = wave & 3;             // q-group 0..3
    const int kh   = wave >> 2;            // k-half 0..1
    const int c    = lane & 31;
    const int hi   = lane >> 5;
    const int hx   = hi * 16;              // byte offset of the 8-elem half
    const int sw   = (c & 7) << 4;         // read-side XOR swizzle

    const int blk = blockIdx.x;
    const int bh  = blk & 31;
    const int qc  = blk >> 5;              // 0..7
    const int q0  = qc * 256 + qg * 64;

    const __bf16* Qp = Q  + ((size_t)bh * Ts + q0) * Dh;
    const __bf16* Kp = K  + (size_t)bh * Ts * Dh;
    const __bf16* Vp = VT + (size_t)bh * Dh * Ts;   // [64][2048]

    // Q fragments (B-operand of mfma(K,Q)), pre-scaled by log2e/sqrt(Dh)
    const float qscale = 0.125f * 1.44269504088896f;
    bf16x8 qf[2][4];
    #pragma unroll
    for (int qs = 0; qs < 2; qs++)
        #pragma unroll
        for (int ds = 0; ds < 4; ds++) {
            bf16x8 v = *(const bf16x8*)(Qp + (qs * 32 + c) * Dh + ds * 16 + hi * 8);
            #pragma unroll
            for (int i = 0; i < 8; i++) v[i] = (__bf16)(qscale * (float)v[i]);
            qf[qs][ds] = v;
        }

    f32x16 accO[2][2];                     // [qs][dt]: O[q][dt*32+c] partial
    #pragma unroll
    for (int qs = 0; qs < 2; qs++)
        #pragma unroll
        for (int dt = 0; dt < 2; dt++)
            #pragma unroll
            for (int i = 0; i < 16; i++) accO[qs][dt][i] = 0.f;
    float lsum[2] = {0.f, 0.f};

    const f32x16 z16 = {0.f, 0.f, 0.f, 0.f, 0.f, 0.f, 0.f, 0.f,
                        0.f, 0.f, 0.f, 0.f, 0.f, 0.f, 0.f, 0.f};

    // staging: linear LDS dest (gll requirement) + permuted global source col
    const int r0 = qg * 8 + (lane >> 3);             // rows 0..31 per kh-half
    const int s8 = ((lane & 7) ^ (r0 & 7)) * 8;      // permuted col (elems)
    const __bf16* kg0 = Kp + (size_t)(kh * 1024 + r0) * Dh + s8;
    const __bf16* kg1 = kg0 + 32 * Dh;               // (32+r0)&7 == r0&7
    const __bf16* vg0 = Vp + (size_t)r0 * Ts + kh * 1024 + s8;
    const __bf16* vg1 = vg0 + (size_t)32 * Ts;

    // prologue: this half's chunk 0 into buf 0
    gll16(kg0, &sK[kh][0][qg * 512]);
    gll16(kg1, &sK[kh][0][2048 + qg * 512]);
    gll16(vg0, &sV[kh][0][qg * 512]);
    gll16(vg1, &sV[kh][0][2048 + qg * 512]);

    for (int j = 0; j < 16; j++) {
        const int p = j % 3;
        if (j < 15) {
            const int pn = (j + 1) % 3;
            gll16(kg0 + (j + 1) * 4096, &sK[kh][pn][qg * 512]);
            gll16(kg1 + (j + 1) * 4096, &sK[kh][pn][2048 + qg * 512]);
            gll16(vg0 + (j + 1) * 64,   &sV[kh][pn][qg * 512]);
            gll16(vg1 + (j + 1) * 64,   &sV[kh][pn][2048 + qg * 512]);
            // chunk j's loads (issued last iter) done; j+1's stay in flight
            asm volatile("s_waitcnt vmcnt(4)" ::: "memory");
        } else {
            asm volatile("s_waitcnt vmcnt(0)" ::: "memory");
        }
        __builtin_amdgcn_s_barrier();          // all waves: chunk j in LDS
        __builtin_amdgcn_sched_barrier(0);     // pin ds_reads below barrier

        const char* kb = (const char*)&sK[kh][p][0];
        const char* vb = (const char*)&sV[kh][p][0];

        // K fragments (A-operand): kf[kt][ds] = K[kt*32+c][ds*16+hi*8 ..+8]
        bf16x8 kf[2][4];
        #pragma unroll
        for (int kt = 0; kt < 2; kt++) {
            const char* rbase = kb + (kt * 32 + c) * 128;
            #pragma unroll
            for (int ds = 0; ds < 4; ds++)
                kf[kt][ds] = *(const bf16x8*)(rbase + ((ds * 32 + hx) ^ sw));
        }

        // QK^T: st[qs][kt] = S^T[k = kt*32 + row][q = qs*32 + c] (log2e-scaled)
        f32x16 st[2][2];
        __builtin_amdgcn_s_setprio(1);
        #pragma unroll
        for (int kt = 0; kt < 2; kt++)
            #pragma unroll
            for (int qs = 0; qs < 2; qs++)
                st[qs][kt] = __builtin_amdgcn_mfma_f32_32x32x16_bf16(
                    kf[kt][0], qf[qs][0], z16, 0, 0, 0);
        #pragma unroll
        for (int ds = 1; ds < 4; ds++)
            #pragma unroll
            for (int kt = 0; kt < 2; kt++)
                #pragma unroll
                for (int qs = 0; qs < 2; qs++)
                    st[qs][kt] = __builtin_amdgcn_mfma_f32_32x32x16_bf16(
                        kf[kt][ds], qf[qs][ds], st[qs][kt], 0, 0, 0);
        __builtin_amdgcn_s_setprio(0);

        // p = exp2(s); pack to bf16 pairs; permlane32_swap builds PV A-frags.
        bf16x8 pa[2][4];
        #pragma unroll
        for (int qs = 0; qs < 2; qs++) {
            unsigned pk[2][8];
            #pragma unroll
            for (int kt = 0; kt < 2; kt++) {
                float sum0 = 0.f, sum1 = 0.f;
                #pragma unroll
                for (int r = 0; r < 16; r++) {
                    float pv = __builtin_amdgcn_exp2f(st[qs][kt][r]);
                    st[qs][kt][r] = pv;
                    if (r & 1) sum1 += pv; else sum0 += pv;
                }
                lsum[qs] += sum0 + sum1;
                #pragma unroll
                for (int r2 = 0; r2 < 8; r2++) {
                    unsigned d;
                    asm("v_cvt_pk_bf16_f32 %0, %1, %2"
                        : "=v"(d)
                        : "v"(st[qs][kt][2 * r2]), "v"(st[qs][kt][2 * r2 + 1]));
                    pk[kt][r2] = d;
                }
            }
            #pragma unroll
            for (int s = 0; s < 4; s++) {
                const int kt = s >> 1, r4 = (s & 1) * 4;
                unsigned x0 = pk[kt][r4 + 0], y0 = pk[kt][r4 + 2];
                unsigned x1 = pk[kt][r4 + 1], y1 = pk[kt][r4 + 3];
                asm("v_permlane32_swap_b32 %0, %1" : "+v"(x0), "+v"(y0));
                asm("v_permlane32_swap_b32 %0, %1" : "+v"(x1), "+v"(y1));
                union { unsigned u[4]; bf16x8 b; } pu;
                pu.u[0] = x0; pu.u[1] = x1; pu.u[2] = y0; pu.u[3] = y1;
                pa[qs][s] = pu.b;
            }
        }

        // PV: vf (B-operand) = V^T[dt*32+c][s*16 + hi*8 + j], shared by qs
        __builtin_amdgcn_s_setprio(1);
        #pragma unroll
        for (int s = 0; s < 4; s++)
            #pragma unroll
            for (int dt = 0; dt < 2; dt++) {
                bf16x8 vf = *(const bf16x8*)(vb + (dt * 32 + c) * 128 +
                                             ((s * 32 + hx) ^ sw));
                #pragma unroll
                for (int qs = 0; qs < 2; qs++)
                    accO[qs][dt] = __builtin_amdgcn_mfma_f32_32x32x16_bf16(
                        pa[qs][s], vf, accO[qs][dt], 0, 0, 0);
            }
        __builtin_amdgcn_s_setprio(0);
        // no trailing barrier: triple-buffer guarantees buf reuse distance 3
    }

    __syncthreads();   // all compute done; staging LDS now dead -> reuse

    // cross-half reduction: kh=1 publishes partials into (dead) staging LDS,
    // kh=0 adds and runs the epilogue. Lane-consecutive f32 -> conflict-free.
    float* pb = (qg < 2) ? (float*)&sK[0][0][0] + qg * 4096
                         : (float*)&sV[0][0][0] + (qg - 2) * 4096;
    if (kh == 1) {
        #pragma unroll
        for (int qs = 0; qs < 2; qs++) {
            #pragma unroll
            for (int dt = 0; dt < 2; dt++)
                #pragma unroll
                for (int r = 0; r < 16; r++)
                    pb[((qs * 2 + dt) << 10) + (r << 6) + lane] = accO[qs][dt][r];
            slsum[qg][qs][lane] = lsum[qs];
        }
    }
    __syncthreads();
    if (kh == 0) {
        #pragma unroll
        for (int qs = 0; qs < 2; qs++) {
            #pragma unroll
            for (int dt = 0; dt < 2; dt++)
                #pragma unroll
                for (int r = 0; r < 16; r++)
                    accO[qs][dt][r] += pb[((qs * 2 + dt) << 10) + (r << 6) + lane];
            lsum[qs] += slsum[qg][qs][lane];
        }

        // epilogue: fold lsum halves, divide, store [B,T,C]
        const int b = bh >> 4, h = bh & 15;
        #pragma unroll
        for (int qs = 0; qs < 2; qs++) {
            float l = lsum[qs] + __shfl_xor(lsum[qs], 32);
            float linv = 1.f / l;
            #pragma unroll
            for (int r = 0; r < 16; r++) {
                const int qrow = (r & 3) + 8 * (r >> 2) + 4 * hi;
                float inv = __shfl(linv, qrow);
                __bf16* Op = O + ((size_t)(b * Ts + q0 + qs * 32 + qrow)) * Cc +
                             h * 64 + c;
                Op[0]  = (__bf16)(accO[qs][0][r] * inv);
                Op[32] = (__bf16)(accO[qs][1][r] * inv);
            }
        }
    }
}

// ---------------------------------------------------------------------------
extern "C" void kernel_launch(void* const* d_in, const int* in_sizes, int n_in,
                              void* d_out, int out_size, void* d_ws, size_t ws_size,
                              hipStream_t stream)
{
    (void)in_sizes; (void)n_in; (void)out_size; (void)ws_size;
    const float* x     = (const float*)d_in[0];
    const float* Wqkv  = (const float*)d_in[1];
    const float* bqkv  = (const float*)d_in[2];
    const float* Wproj = (const float*)d_in[3];
    const float* bproj = (const float*)d_in[4];
    float* out = (float*)d_out;

    __bf16* ws   = (__bf16*)d_ws;
    __bf16* Qw   = ws;                          // Q,K [B,H,T,Dh]; V^T [B,H,Dh,T]
    __bf16* XbAO = ws + 3 * (size_t)BHTD;       // Xb then AO (union)  8 MB
    __bf16* Wqt  = XbAO + (size_t)Mm * Cc;      // [3072][1024]        6 MB
    __bf16* Wpt  = Wqt + (size_t)Nqkv * Cc;     // [1024][1024]        2 MB

    prep_all<<<dim3(2048), 256, 0, stream>>>(x, XbAO, Wqkv, Wqt, Wproj, Wpt);
    qkv_mfma<<<dim3(192), 512, 0, stream>>>(XbAO, Wqt, bqkv, Qw);
    attn_mfma<<<dim3(256), 512, 0, stream>>>(
        Qw, Qw + BHTD, Qw + 2 * (size_t)BHTD, XbAO);   // AO overwrites Xb (dead)
    proj_mfma<<<dim3(256), 256, 0, stream>>>(XbAO, Wpt, bproj, out);
}